// Round 1
// baseline (13914.795 us; speedup 1.0000x reference)
//
#include <hip/hip_runtime.h>
#include <hip/hip_bf16.h>

// LatticeLSTM on MI355X.
// Design: 8 sequences x 32 WGs (grid 256 x 256thr). Each WG owns 16 H-columns.
// Weights converted once per launch to bf16 and transposed (column-major rows)
// into d_ws so each 16-lane group reads contiguous rows. Sequential T-loop with
// per-sequence spin barriers (2 per step) using relaxed agent-scope atomics;
// shared state (h rows in d_out, pend ring) uses sc1 coherent loads/stores so
// weight caching in L1/L2 is never invalidated.
//
// pmask is data-independent: m0=(t>=1), m1=(t>=3); c_plain only at t=0.

#define Bq 8
#define Tq 1024
#define DCq 128
#define Hq 512
#define NWG 32
#define NTHR 256

// ws byte offsets (all 256B-aligned)
#define SYNC_OFF  0u
#define PEND_OFF  1024u        // 8*4*2*512*4 = 131072
#define WIHT_OFF  132096u      // bf16 [1536][128]
#define WHHT_OFF  525312u      // bf16 [1536][512]
#define AWIHT_OFF 2098176u     // bf16 [512][128]
#define AWHHT_OFF 2229248u     // bf16 [512][512]
#define WWIHT_OFF 2753536u     // bf16 [1536][128]
#define WWHHT_OFF 3146752u     // bf16 [1536][512]  (end 4719616)

__device__ __forceinline__ float bflo(unsigned u){ return __uint_as_float(u << 16); }
__device__ __forceinline__ float bfhi(unsigned u){ return __uint_as_float(u & 0xffff0000u); }
__device__ __forceinline__ float sigm(float x){ return 1.0f / (1.0f + __expf(-x)); }

__device__ __forceinline__ void fma4(float& acc, uint2 w, float4 v){
  acc = fmaf(bflo(w.x), v.x, acc);
  acc = fmaf(bfhi(w.x), v.y, acc);
  acc = fmaf(bflo(w.y), v.z, acc);
  acc = fmaf(bfhi(w.y), v.w, acc);
}

__device__ __forceinline__ float red16(float x){
  x += __shfl_xor(x, 8, 16);
  x += __shfl_xor(x, 4, 16);
  x += __shfl_xor(x, 2, 16);
  x += __shfl_xor(x, 1, 16);
  return x;
}

// coherent (agent-scope, sc1) load/store for cross-WG shared data
__device__ __forceinline__ float gload(const float* p){
  return __hip_atomic_load(p, __ATOMIC_RELAXED, __HIP_MEMORY_SCOPE_AGENT);
}
__device__ __forceinline__ void gstore(float* p, float v){
  __hip_atomic_store(p, v, __ATOMIC_RELAXED, __HIP_MEMORY_SCOPE_AGENT);
}

// Per-sequence spin barrier. Monotonic generation counter; cnt never resets.
// __syncthreads() emits s_waitcnt vmcnt(0) before s_barrier, so all waves'
// sc1 stores are globally visible before the (relaxed) arrival add.
__device__ __forceinline__ void seq_barrier(unsigned* cnt, unsigned* gen, unsigned target){
  __syncthreads();
  if (threadIdx.x == 0){
    unsigned old = __hip_atomic_fetch_add(cnt, 1u, __ATOMIC_RELAXED, __HIP_MEMORY_SCOPE_AGENT);
    if (old == target * NWG - 1u){
      __hip_atomic_store(gen, target, __ATOMIC_RELAXED, __HIP_MEMORY_SCOPE_AGENT);
    } else {
      while (__hip_atomic_load(gen, __ATOMIC_RELAXED, __HIP_MEMORY_SCOPE_AGENT) < target){
        __builtin_amdgcn_s_sleep(2);
      }
    }
  }
  __syncthreads();
}

// src [K][N] fp32 -> dst [N][K] bf16 (transpose + convert). K is pow2.
__global__ void transpose_bf16(const float* __restrict__ src, __hip_bfloat16* __restrict__ dst,
                               int kshift, int total, int N){
  const int K = 1 << kshift;
  for (int idx = blockIdx.x * blockDim.x + threadIdx.x; idx < total;
       idx += gridDim.x * blockDim.x){
    int n = idx >> kshift;
    int k = idx & (K - 1);
    dst[idx] = __float2bfloat16(src[(size_t)k * N + n]);
  }
}

__global__ void __launch_bounds__(NTHR)
lattice_main(const float* __restrict__ char_emb,
             const int*   __restrict__ word_ids,
             const float* __restrict__ sense_table,
             const float* __restrict__ bias_b,
             const float* __restrict__ bias_ab,
             const float* __restrict__ bias_wb,
             unsigned char* __restrict__ ws,
             float* __restrict__ out)
{
  const int seq  = blockIdx.y;
  const int wg   = blockIdx.x;
  const int tid  = threadIdx.x;
  const int grp  = tid >> 4;
  const int lane = tid & 15;
  const int J    = wg * 16 + grp;     // owned H column

  unsigned* cnt = (unsigned*)(ws + SYNC_OFF) + (size_t)seq * 32;  // 128B apart per seq
  unsigned* gen = cnt + 16;                                       // separate 64B line

  float* pend = (float*)(ws + PEND_OFF) + (size_t)seq * 4 * 2 * Hq; // [slot][k][col]

  const uint2* w_ihT  = (const uint2*)(ws + WIHT_OFF);
  const uint2* w_hhT  = (const uint2*)(ws + WHHT_OFF);
  const uint2* aw_ihT = (const uint2*)(ws + AWIHT_OFF);
  const uint2* aw_hhT = (const uint2*)(ws + AWHHT_OFF);
  const uint2* ww_ihT = (const uint2*)(ws + WWIHT_OFF);
  const uint2* ww_hhT = (const uint2*)(ws + WWHHT_OFF);

  // row pointers (512-col rows = 128 uint2, 128-col rows = 32 uint2)
  const uint2* whh_i = w_hhT  + (size_t)(0*Hq + J) * 128;
  const uint2* whh_o = w_hhT  + (size_t)(1*Hq + J) * 128;
  const uint2* whh_g = w_hhT  + (size_t)(2*Hq + J) * 128;
  const uint2* awhh  = aw_hhT + (size_t)J * 128;
  const uint2* wwh_f = ww_hhT + (size_t)(0*Hq + J) * 128;
  const uint2* wwh_i = ww_hhT + (size_t)(1*Hq + J) * 128;
  const uint2* wwh_g = ww_hhT + (size_t)(2*Hq + J) * 128;
  const uint2* wih_i = w_ihT  + (size_t)(0*Hq + J) * 32;
  const uint2* wih_o = w_ihT  + (size_t)(1*Hq + J) * 32;
  const uint2* wih_g = w_ihT  + (size_t)(2*Hq + J) * 32;
  const uint2* awih  = aw_ihT + (size_t)J * 32;
  const uint2* wwi_f = ww_ihT + (size_t)(0*Hq + J) * 32;
  const uint2* wwi_i = ww_ihT + (size_t)(1*Hq + J) * 32;
  const uint2* wwi_g = ww_ihT + (size_t)(2*Hq + J) * 32;

  const float b_i  = bias_b[J], b_o = bias_b[Hq + J], b_g = bias_b[2*Hq + J];
  const float ab_J = bias_ab[J];
  const float wb_f = bias_wb[J], wb_i = bias_wb[Hq + J], wb_g = bias_wb[2*Hq + J];

  float* out_h = out + (size_t)seq * Tq * Hq;            // hs block
  float* out_c = out + ((size_t)Bq + seq) * Tq * Hq;     // cs block

  __shared__ __align__(16) float sh_h[Hq];
  __shared__ __align__(16) float sh_p0[Hq];
  __shared__ __align__(16) float sh_p1[Hq];
  __shared__ __align__(16) float sh_x[DCq];
  __shared__ __align__(16) float sh_xw0[DCq];
  __shared__ __align__(16) float sh_xw1[DCq];

  unsigned bgen = 0;

  for (int t = 0; t < Tq; ++t){
    const int r = t & 3;
    // ---- stage phase A inputs ----
    {
      const float* hsrc = out_h + (size_t)(t - 1) * Hq;
      const float* p0 = pend + (r * 2 + 0) * Hq;
      const float* p1 = pend + (r * 2 + 1) * Hq;
      for (int i = tid; i < Hq; i += NTHR){
        sh_h[i]  = (t == 0) ? 0.0f : gload(hsrc + i);
        sh_p0[i] = gload(p0 + i);
        sh_p1[i] = gload(p1 + i);
      }
      if (tid < DCq) sh_x[tid] = char_emb[((size_t)seq * Tq + t) * DCq + tid];
    }
    __syncthreads();

    // ---- char-cell dots: i,o,g over h (K=512) + alpha over pend + input parts ----
    float a_i = 0.f, a_o = 0.f, a_g = 0.f, a_p0 = 0.f, a_p1 = 0.f, a_xa = 0.f;
    for (int it = 0; it < 8; ++it){
      const int k0 = it * 64 + lane * 4;   // 4 consecutive k per lane: 2-way LDS aliasing (free)
      const int q  = k0 >> 2;
      float4 hv  = *(const float4*)(sh_h  + k0);
      float4 p0v = *(const float4*)(sh_p0 + k0);
      float4 p1v = *(const float4*)(sh_p1 + k0);
      fma4(a_i, whh_i[q], hv);
      fma4(a_o, whh_o[q], hv);
      fma4(a_g, whh_g[q], hv);
      uint2 aw = awhh[q];
      fma4(a_p0, aw, p0v);
      fma4(a_p1, aw, p1v);
    }
    for (int it = 0; it < 2; ++it){
      const int k0 = it * 64 + lane * 4;
      const int q  = k0 >> 2;
      float4 xv = *(const float4*)(sh_x + k0);
      fma4(a_i,  wih_i[q], xv);
      fma4(a_o,  wih_o[q], xv);
      fma4(a_g,  wih_g[q], xv);
      fma4(a_xa, awih[q],  xv);
    }
    a_i  = red16(a_i);  a_o  = red16(a_o);  a_g  = red16(a_g);
    a_p0 = red16(a_p0); a_p1 = red16(a_p1); a_xa = red16(a_xa);

    const float gi = sigm(a_i + b_i);
    const float go = sigm(a_o + b_o);
    const float gg = tanhf(a_g + b_g);
    float c1;
    if (t == 0){
      c1 = gi * gg;                       // c_plain with c=0
    } else {
      const float base = a_xa + ab_J;
      const float ea0 = __expf(sigm(base + a_p0));   // m0 = 1 for t>=1
      const float ei  = __expf(gi);
      float num = ei * gg + ea0 * sh_p0[J];
      float den = ei + ea0;
      if (t >= 3){                                    // m1 = 1 for t>=3
        const float ea1 = __expf(sigm(base + a_p1));
        num += ea1 * sh_p1[J];
        den += ea1;
      }
      c1 = num / den;
    }
    const float h1 = go * tanhf(c1);
    if (lane == 0){
      gstore(out_h + (size_t)t * Hq + J, h1);   // read by peers: coherent store
      out_c[(size_t)t * Hq + J] = c1;           // only harness reads: plain store
    }
    ++bgen;
    seq_barrier(cnt, gen, bgen);

    // ---- word-cell: wg = xw@ww_ih + h1@ww_hh + wb ----
    {
      const float* h1src = out_h + (size_t)t * Hq;
      for (int i = tid; i < Hq; i += NTHR) sh_h[i] = gload(h1src + i);
      if (tid < DCq){
        const int w0 = word_ids[((size_t)seq * Tq + t) * 2 + 0];
        sh_xw0[tid] = sense_table[(size_t)w0 * DCq + tid];
      } else {
        const int w1 = word_ids[((size_t)seq * Tq + t) * 2 + 1];
        sh_xw1[tid - DCq] = sense_table[(size_t)w1 * DCq + (tid - DCq)];
      }
    }
    __syncthreads();

    float r_f = 0.f, r_i = 0.f, r_g = 0.f;
    float x_f0 = 0.f, x_i0 = 0.f, x_g0 = 0.f, x_f1 = 0.f, x_i1 = 0.f, x_g1 = 0.f;
    for (int it = 0; it < 8; ++it){
      const int k0 = it * 64 + lane * 4;
      const int q  = k0 >> 2;
      float4 hv = *(const float4*)(sh_h + k0);
      fma4(r_f, wwh_f[q], hv);
      fma4(r_i, wwh_i[q], hv);
      fma4(r_g, wwh_g[q], hv);
    }
    for (int it = 0; it < 2; ++it){
      const int k0 = it * 64 + lane * 4;
      const int q  = k0 >> 2;
      float4 x0 = *(const float4*)(sh_xw0 + k0);
      float4 x1 = *(const float4*)(sh_xw1 + k0);
      uint2 wf = wwi_f[q], wi = wwi_i[q], wgq = wwi_g[q];
      fma4(x_f0, wf, x0);  fma4(x_f1, wf, x1);
      fma4(x_i0, wi, x0);  fma4(x_i1, wi, x1);
      fma4(x_g0, wgq, x0); fma4(x_g1, wgq, x1);
    }
    r_f  = red16(r_f);  r_i  = red16(r_i);  r_g  = red16(r_g);
    x_f0 = red16(x_f0); x_i0 = red16(x_i0); x_g0 = red16(x_g0);
    x_f1 = red16(x_f1); x_i1 = red16(x_i1); x_g1 = red16(x_g1);

    if (lane == 0){
      const float f0  = sigm(r_f + x_f0 + wb_f);
      const float i0  = sigm(r_i + x_i0 + wb_i);
      const float g0  = tanhf(r_g + x_g0 + wb_g);
      const float cw0 = f0 * c1 + i0 * g0;
      const float f1  = sigm(r_f + x_f1 + wb_f);
      const float i1  = sigm(r_i + x_i1 + wb_i);
      const float g1  = tanhf(r_g + x_g1 + wb_g);
      const float cw1 = f1 * c1 + i1 * g1;
      // unconditional ring writes; invalid (t near T) slots are never read
      gstore(pend + (((t + 1) & 3) * 2 + 0) * Hq + J, cw0);
      gstore(pend + (((t + 3) & 3) * 2 + 1) * Hq + J, cw1);
    }
    ++bgen;
    seq_barrier(cnt, gen, bgen);
  }
}

extern "C" void kernel_launch(void* const* d_in, const int* in_sizes, int n_in,
                              void* d_out, int out_size, void* d_ws, size_t ws_size,
                              hipStream_t stream){
  const float* char_emb = (const float*)d_in[0];
  const int*   word_ids = (const int*)d_in[1];
  const float* sense    = (const float*)d_in[2];
  const float* w_ih     = (const float*)d_in[3];
  const float* w_hh     = (const float*)d_in[4];
  const float* bb       = (const float*)d_in[5];
  const float* aw_ih    = (const float*)d_in[6];
  const float* aw_hh    = (const float*)d_in[7];
  const float* ab       = (const float*)d_in[8];
  const float* ww_ih    = (const float*)d_in[9];
  const float* ww_hh    = (const float*)d_in[10];
  const float* wb       = (const float*)d_in[11];
  unsigned char* ws = (unsigned char*)d_ws;
  float* out = (float*)d_out;

  // zero sync counters + pend ring (ws is re-poisoned before every launch)
  hipMemsetAsync(ws, 0, WIHT_OFF, stream);

  // one-time (per launch) weight convert+transpose to bf16
  transpose_bf16<<<512, NTHR, 0, stream>>>(w_ih,  (__hip_bfloat16*)(ws + WIHT_OFF),  7, 128*1536, 1536);
  transpose_bf16<<<512, NTHR, 0, stream>>>(w_hh,  (__hip_bfloat16*)(ws + WHHT_OFF),  9, 512*1536, 1536);
  transpose_bf16<<<512, NTHR, 0, stream>>>(aw_ih, (__hip_bfloat16*)(ws + AWIHT_OFF), 7, 128*512,  512);
  transpose_bf16<<<512, NTHR, 0, stream>>>(aw_hh, (__hip_bfloat16*)(ws + AWHHT_OFF), 9, 512*512,  512);
  transpose_bf16<<<512, NTHR, 0, stream>>>(ww_ih, (__hip_bfloat16*)(ws + WWIHT_OFF), 7, 128*1536, 1536);
  transpose_bf16<<<512, NTHR, 0, stream>>>(ww_hh, (__hip_bfloat16*)(ws + WWHHT_OFF), 9, 512*1536, 1536);

  dim3 grid(NWG, Bq);   // 32 WGs per sequence x 8 sequences = 256 WGs (all co-resident)
  lattice_main<<<grid, NTHR, 0, stream>>>(char_emb, word_ids, sense, bb, ab, wb, ws, out);
}